// Round 1
// baseline (784.975 us; speedup 1.0000x reference)
//
#include <hip/hip_runtime.h>
#include <hip/hip_bf16.h>

#define N_NODES 100000
#define F_IN    512
#define H1      8
#define C1      8
#define D1      64   // H1*C1
#define C2      16
#define SLOPE   0.2f

// ---------------------------------------------------------------------------
// GEMM1: hp1[N,64] = x[N,512] @ W1[512,64]   (fp32, tiled 64x64, BK=16)
// ---------------------------------------------------------------------------
__global__ __launch_bounds__(256) void gemm1_kernel(
    const float* __restrict__ X, const float* __restrict__ W,
    float* __restrict__ HP, int n)
{
    __shared__ float As[16][68];  // [k][m], +4 pad keeps float4 align, kills conflicts
    __shared__ float Bs[16][68];  // [k][n]

    const int t = threadIdx.x;
    const int rowbase = blockIdx.x * 64;
    const int m0 = (t >> 4) << 2;   // 0..60
    const int n0 = (t & 15) << 2;   // 0..60

    // A-load mapping: row lr (0..63), k-chunk lk (0,4,8,12)
    const int lr = t >> 2;
    const int lk = (t & 3) << 2;
    // B-load mapping: k bk (0..15), col bn
    const int bk = t >> 4;
    const int bn = (t & 15) << 2;

    const bool arow_ok = (rowbase + lr) < n;
    const float* xrow = X + (size_t)(rowbase + lr) * F_IN;

    float acc[4][4] = {};

    for (int k0 = 0; k0 < F_IN; k0 += 16) {
        float4 av = arow_ok ? *(const float4*)(xrow + k0 + lk)
                            : make_float4(0.f, 0.f, 0.f, 0.f);
        float4 bv = *(const float4*)(W + (size_t)(k0 + bk) * D1 + bn);
        __syncthreads();
        As[lk + 0][lr] = av.x;
        As[lk + 1][lr] = av.y;
        As[lk + 2][lr] = av.z;
        As[lk + 3][lr] = av.w;
        *(float4*)&Bs[bk][bn] = bv;
        __syncthreads();
#pragma unroll
        for (int k = 0; k < 16; ++k) {
            float4 a = *(const float4*)&As[k][m0];
            float4 b = *(const float4*)&Bs[k][n0];
            acc[0][0] += a.x * b.x; acc[0][1] += a.x * b.y; acc[0][2] += a.x * b.z; acc[0][3] += a.x * b.w;
            acc[1][0] += a.y * b.x; acc[1][1] += a.y * b.y; acc[1][2] += a.y * b.z; acc[1][3] += a.y * b.w;
            acc[2][0] += a.z * b.x; acc[2][1] += a.z * b.y; acc[2][2] += a.z * b.z; acc[2][3] += a.z * b.w;
            acc[3][0] += a.w * b.x; acc[3][1] += a.w * b.y; acc[3][2] += a.w * b.z; acc[3][3] += a.w * b.w;
        }
    }

#pragma unroll
    for (int i = 0; i < 4; ++i) {
        int r = rowbase + m0 + i;
        if (r < n) {
            *(float4*)&HP[(size_t)r * D1 + n0] =
                make_float4(acc[i][0], acc[i][1], acc[i][2], acc[i][3]);
        }
    }
}

// ---------------------------------------------------------------------------
// al1: al_s1[n,h] = dot(hp1[n,h,:], a1_src[h,:]), same for dst.  i = n*8+h
// ---------------------------------------------------------------------------
__global__ void al1_kernel(const float* __restrict__ hp,
                           const float* __restrict__ asrc,
                           const float* __restrict__ adst,
                           float* __restrict__ als, float* __restrict__ ald,
                           int n8)
{
    int i = blockIdx.x * 256 + threadIdx.x;
    if (i >= n8) return;
    int h = i & 7;
    const float* p = hp + (size_t)i * 8;   // == n*64 + h*8
    float4 v0 = *(const float4*)p;
    float4 v1 = *(const float4*)(p + 4);
    const float* s = asrc + h * 8;
    const float* d = adst + h * 8;
    float rs = v0.x*s[0] + v0.y*s[1] + v0.z*s[2] + v0.w*s[3]
             + v1.x*s[4] + v1.y*s[5] + v1.z*s[6] + v1.w*s[7];
    float rd = v0.x*d[0] + v0.y*d[1] + v0.z*d[2] + v0.w*d[3]
             + v1.x*d[4] + v1.y*d[5] + v1.z*d[6] + v1.w*d[7];
    als[i] = rs;
    ald[i] = rd;
}

// ---------------------------------------------------------------------------
// CSR build
// ---------------------------------------------------------------------------
__global__ void count_deg_kernel(const int* __restrict__ ei, int* __restrict__ deg,
                                 int E, int total)
{
    int e = blockIdx.x * 256 + threadIdx.x;
    if (e >= total) return;
    int dst = (e < E) ? ei[E + e] : (e - E);   // self-loop: dst = node
    atomicAdd(&deg[dst], 1);
}

__global__ void block_sums_kernel(const int* __restrict__ deg, int* __restrict__ partial, int n)
{
    int b = blockIdx.x, t = threadIdx.x;
    int base = b * 1024 + t * 4;
    int s = 0;
#pragma unroll
    for (int j = 0; j < 4; ++j) { int idx = base + j; s += (idx < n) ? deg[idx] : 0; }
    for (int off = 32; off > 0; off >>= 1) s += __shfl_down(s, off, 64);
    __shared__ int ws[4];
    if ((t & 63) == 0) ws[t >> 6] = s;
    __syncthreads();
    if (t == 0) partial[b] = ws[0] + ws[1] + ws[2] + ws[3];
}

__global__ void scan_partials_kernel(const int* __restrict__ partial,
                                     int* __restrict__ blockoff, int nb)
{
    if (threadIdx.x == 0 && blockIdx.x == 0) {
        int s = 0;
        for (int i = 0; i < nb; ++i) { blockoff[i] = s; s += partial[i]; }
    }
}

__global__ void scan_block_kernel(const int* __restrict__ deg,
                                  const int* __restrict__ blockoff,
                                  int* __restrict__ offsets, int n, int total)
{
    __shared__ int sdata[256];
    int b = blockIdx.x, t = threadIdx.x;
    int base = b * 1024 + t * 4;
    int v[4];
    int s = 0;
#pragma unroll
    for (int j = 0; j < 4; ++j) { int idx = base + j; v[j] = (idx < n) ? deg[idx] : 0; s += v[j]; }
    sdata[t] = s;
    __syncthreads();
    for (int off = 1; off < 256; off <<= 1) {
        int x = (t >= off) ? sdata[t - off] : 0;
        __syncthreads();
        sdata[t] += x;
        __syncthreads();
    }
    int run = ((t == 0) ? 0 : sdata[t - 1]) + blockoff[b];
#pragma unroll
    for (int j = 0; j < 4; ++j) {
        int idx = base + j;
        if (idx < n) offsets[idx] = run;
        run += v[j];
    }
    if (b == 0 && t == 0) offsets[n] = total;
}

__global__ void copy_cursor_kernel(const int* __restrict__ offsets,
                                   int* __restrict__ cursor, int n)
{
    int i = blockIdx.x * 256 + threadIdx.x;
    if (i < n) cursor[i] = offsets[i];
}

__global__ void scatter_kernel(const int* __restrict__ ei, int* __restrict__ cursor,
                               int* __restrict__ csr, int E, int total)
{
    int e = blockIdx.x * 256 + threadIdx.x;
    if (e >= total) return;
    int src, dst;
    if (e < E) { src = ei[e]; dst = ei[E + e]; }
    else       { src = dst = e - E; }
    int p = atomicAdd(&cursor[dst], 1);
    csr[p] = src;
}

// ---------------------------------------------------------------------------
// agg1: one wave per dst node.  lane = h*8+c.
// out = elu( (sum_e ee*hp1[src]) / (sum_e ee) + b1 )
// ---------------------------------------------------------------------------
__global__ __launch_bounds__(256) void agg1_kernel(
    const float* __restrict__ hp1,
    const float* __restrict__ als, const float* __restrict__ ald,
    const int* __restrict__ offsets, const int* __restrict__ csr,
    const float* __restrict__ b1,
    float* __restrict__ h1, int n)
{
    int node = blockIdx.x * 4 + (threadIdx.x >> 6);
    if (node >= n) return;
    int lane = threadIdx.x & 63;
    int h = lane >> 3;

    int beg = offsets[node], end = offsets[node + 1];
    float ad = ald[node * 8 + h];
    float den = 0.f, acc = 0.f;
    for (int i = beg; i < end; ++i) {
        int s = csr[i];
        float e = als[s * 8 + h] + ad;
        e = (e > 0.f) ? e : SLOPE * e;
        float ee = __expf(e);
        den += ee;
        acc += ee * hp1[(size_t)s * D1 + lane];
    }
    float v = acc / den + b1[lane];
    v = (v > 0.f) ? v : (__expf(v) - 1.f);    // ELU
    h1[(size_t)node * D1 + lane] = v;
}

// ---------------------------------------------------------------------------
// GEMM2: hp2[N,16] = h1[N,64] @ W2[64,16]
// ---------------------------------------------------------------------------
__global__ __launch_bounds__(256) void gemm2_kernel(
    const float* __restrict__ H, const float* __restrict__ W2,
    float* __restrict__ HP2, int n)
{
    __shared__ float Ws[64 * 16];
    int t = threadIdx.x;
    for (int i = t; i < 1024; i += 256) Ws[i] = W2[i];
    __syncthreads();
    int idx = blockIdx.x * 256 + t;        // node*16 + c
    int node = idx >> 4, c = idx & 15;
    if (node >= n) return;
    const float* hr = H + (size_t)node * D1;
    float acc = 0.f;
#pragma unroll 8
    for (int k = 0; k < 64; ++k) acc += hr[k] * Ws[k * 16 + c];
    HP2[idx] = acc;
}

__global__ void al2_kernel(const float* __restrict__ hp2,
                           const float* __restrict__ a2s,
                           const float* __restrict__ a2d,
                           float* __restrict__ als, float* __restrict__ ald, int n)
{
    int i = blockIdx.x * 256 + threadIdx.x;
    if (i >= n) return;
    const float* p = hp2 + (size_t)i * 16;
    float rs = 0.f, rd = 0.f;
#pragma unroll
    for (int k = 0; k < 16; ++k) { float v = p[k]; rs += v * a2s[k]; rd += v * a2d[k]; }
    als[i] = rs;
    ald[i] = rd;
}

// ---------------------------------------------------------------------------
// agg2 + log_softmax: 16 lanes per dst node (4 nodes per wave)
// ---------------------------------------------------------------------------
__global__ __launch_bounds__(256) void agg2_kernel(
    const float* __restrict__ hp2,
    const float* __restrict__ als, const float* __restrict__ ald,
    const int* __restrict__ offsets, const int* __restrict__ csr,
    const float* __restrict__ b2,
    float* __restrict__ out, int n)
{
    int node = blockIdx.x * 16 + (threadIdx.x >> 4);
    if (node >= n) return;
    int c = threadIdx.x & 15;

    int beg = offsets[node], end = offsets[node + 1];
    float ad = ald[node];
    float den = 0.f, acc = 0.f;
    for (int i = beg; i < end; ++i) {
        int s = csr[i];
        float e = als[s] + ad;
        e = (e > 0.f) ? e : SLOPE * e;
        float ee = __expf(e);
        den += ee;
        acc += ee * hp2[(size_t)s * 16 + c];
    }
    float v = acc / den + b2[c];

    // log_softmax over the 16 lanes of this node
    float m = v;
    m = fmaxf(m, __shfl_xor(m, 8, 16));
    m = fmaxf(m, __shfl_xor(m, 4, 16));
    m = fmaxf(m, __shfl_xor(m, 2, 16));
    m = fmaxf(m, __shfl_xor(m, 1, 16));
    float ex = __expf(v - m);
    float sum = ex;
    sum += __shfl_xor(sum, 8, 16);
    sum += __shfl_xor(sum, 4, 16);
    sum += __shfl_xor(sum, 2, 16);
    sum += __shfl_xor(sum, 1, 16);
    out[(size_t)node * 16 + c] = v - m - __logf(sum);
}

// ---------------------------------------------------------------------------
extern "C" void kernel_launch(void* const* d_in, const int* in_sizes, int n_in,
                              void* d_out, int out_size, void* d_ws, size_t ws_size,
                              hipStream_t stream)
{
    const float* x      = (const float*)d_in[0];
    const int*   ei     = (const int*)  d_in[1];
    const float* W1     = (const float*)d_in[2];
    const float* a1_src = (const float*)d_in[3];
    const float* a1_dst = (const float*)d_in[4];
    const float* b1     = (const float*)d_in[5];
    const float* W2     = (const float*)d_in[6];
    const float* a2_src = (const float*)d_in[7];
    const float* a2_dst = (const float*)d_in[8];
    const float* b2     = (const float*)d_in[9];
    float* out = (float*)d_out;

    const int N = in_sizes[0] / F_IN;       // 100000
    const int E = in_sizes[1] / 2;          // 1600000
    const int TOT = E + N;                  // edges incl self-loops

    // workspace carve-up (256B aligned)
    char* base = (char*)d_ws;
    size_t off = 0;
    auto carve = [&](size_t bytes) -> char* {
        char* p = base + off;
        off += (bytes + 255) & ~(size_t)255;
        return p;
    };
    float* hp1     = (float*)carve((size_t)N * D1 * 4);
    float* h1      = (float*)carve((size_t)N * D1 * 4);
    float* hp2     = (float*)carve((size_t)N * 16 * 4);
    float* als1    = (float*)carve((size_t)N * 8 * 4);
    float* ald1    = (float*)carve((size_t)N * 8 * 4);
    float* als2    = (float*)carve((size_t)N * 4);
    float* ald2    = (float*)carve((size_t)N * 4);
    int*   deg     = (int*)  carve((size_t)N * 4);
    int*   offsets = (int*)  carve((size_t)(N + 1) * 4);
    int*   cursor  = (int*)  carve((size_t)N * 4);
    int*   partial = (int*)  carve(4096);
    int*   blockoff= (int*)  carve(4096);
    int*   csr     = (int*)  carve((size_t)TOT * 4);

    const int nScanBlocks = (N + 1023) / 1024;       // 98
    const int nEdgeBlocks = (TOT + 255) / 256;

    hipMemsetAsync(deg, 0, (size_t)N * 4, stream);

    gemm1_kernel<<<(N + 63) / 64, 256, 0, stream>>>(x, W1, hp1, N);
    al1_kernel<<<(N * 8 + 255) / 256, 256, 0, stream>>>(hp1, a1_src, a1_dst, als1, ald1, N * 8);

    count_deg_kernel<<<nEdgeBlocks, 256, 0, stream>>>(ei, deg, E, TOT);
    block_sums_kernel<<<nScanBlocks, 256, 0, stream>>>(deg, partial, N);
    scan_partials_kernel<<<1, 64, 0, stream>>>(partial, blockoff, nScanBlocks);
    scan_block_kernel<<<nScanBlocks, 256, 0, stream>>>(deg, blockoff, offsets, N, TOT);
    copy_cursor_kernel<<<(N + 255) / 256, 256, 0, stream>>>(offsets, cursor, N);
    scatter_kernel<<<nEdgeBlocks, 256, 0, stream>>>(ei, cursor, csr, E, TOT);

    agg1_kernel<<<(N + 3) / 4, 256, 0, stream>>>(hp1, als1, ald1, offsets, csr, b1, h1, N);

    gemm2_kernel<<<(N * 16 + 255) / 256, 256, 0, stream>>>(h1, W2, hp2, N);
    al2_kernel<<<(N + 255) / 256, 256, 0, stream>>>(hp2, a2_src, a2_dst, als2, ald2, N);

    agg2_kernel<<<(N + 15) / 16, 256, 0, stream>>>(hp2, als2, ald2, offsets, csr, b2, out, N);
}

// Round 2
// 668.400 us; speedup vs baseline: 1.1744x; 1.1744x over previous
//
#include <hip/hip_runtime.h>
#include <hip/hip_bf16.h>

#define N_NODES 100000
#define F_IN    512
#define H1      8
#define C1      8
#define D1      64   // H1*C1
#define C2      16
#define SLOPE   0.2f

// ---------------------------------------------------------------------------
// GEMM1: hp1[N,64] = x[N,512] @ W1[512,64]   (fp32, tiled 64x64, BK=16)
// ---------------------------------------------------------------------------
__global__ __launch_bounds__(256) void gemm1_kernel(
    const float* __restrict__ X, const float* __restrict__ W,
    float* __restrict__ HP, int n)
{
    __shared__ float As[16][68];  // [k][m], +4 pad keeps float4 align, kills conflicts
    __shared__ float Bs[16][68];  // [k][n]

    const int t = threadIdx.x;
    const int rowbase = blockIdx.x * 64;
    const int m0 = (t >> 4) << 2;   // 0..60
    const int n0 = (t & 15) << 2;   // 0..60

    const int lr = t >> 2;
    const int lk = (t & 3) << 2;
    const int bk = t >> 4;
    const int bn = (t & 15) << 2;

    const bool arow_ok = (rowbase + lr) < n;
    const float* xrow = X + (size_t)(rowbase + lr) * F_IN;

    float acc[4][4] = {};

    for (int k0 = 0; k0 < F_IN; k0 += 16) {
        float4 av = arow_ok ? *(const float4*)(xrow + k0 + lk)
                            : make_float4(0.f, 0.f, 0.f, 0.f);
        float4 bv = *(const float4*)(W + (size_t)(k0 + bk) * D1 + bn);
        __syncthreads();
        As[lk + 0][lr] = av.x;
        As[lk + 1][lr] = av.y;
        As[lk + 2][lr] = av.z;
        As[lk + 3][lr] = av.w;
        *(float4*)&Bs[bk][bn] = bv;
        __syncthreads();
#pragma unroll
        for (int k = 0; k < 16; ++k) {
            float4 a = *(const float4*)&As[k][m0];
            float4 b = *(const float4*)&Bs[k][n0];
            acc[0][0] += a.x * b.x; acc[0][1] += a.x * b.y; acc[0][2] += a.x * b.z; acc[0][3] += a.x * b.w;
            acc[1][0] += a.y * b.x; acc[1][1] += a.y * b.y; acc[1][2] += a.y * b.z; acc[1][3] += a.y * b.w;
            acc[2][0] += a.z * b.x; acc[2][1] += a.z * b.y; acc[2][2] += a.z * b.z; acc[2][3] += a.z * b.w;
            acc[3][0] += a.w * b.x; acc[3][1] += a.w * b.y; acc[3][2] += a.w * b.z; acc[3][3] += a.w * b.w;
        }
    }

#pragma unroll
    for (int i = 0; i < 4; ++i) {
        int r = rowbase + m0 + i;
        if (r < n) {
            *(float4*)&HP[(size_t)r * D1 + n0] =
                make_float4(acc[i][0], acc[i][1], acc[i][2], acc[i][3]);
        }
    }
}

// ---------------------------------------------------------------------------
// al1: al_s1[n,h] = dot(hp1[n,h,:], a1_src[h,:]), same for dst.  i = n*8+h
// ---------------------------------------------------------------------------
__global__ void al1_kernel(const float* __restrict__ hp,
                           const float* __restrict__ asrc,
                           const float* __restrict__ adst,
                           float* __restrict__ als, float* __restrict__ ald,
                           int n8)
{
    int i = blockIdx.x * 256 + threadIdx.x;
    if (i >= n8) return;
    int h = i & 7;
    const float* p = hp + (size_t)i * 8;   // == n*64 + h*8
    float4 v0 = *(const float4*)p;
    float4 v1 = *(const float4*)(p + 4);
    const float* s = asrc + h * 8;
    const float* d = adst + h * 8;
    float rs = v0.x*s[0] + v0.y*s[1] + v0.z*s[2] + v0.w*s[3]
             + v1.x*s[4] + v1.y*s[5] + v1.z*s[6] + v1.w*s[7];
    float rd = v0.x*d[0] + v0.y*d[1] + v0.z*d[2] + v0.w*d[3]
             + v1.x*d[4] + v1.y*d[5] + v1.z*d[6] + v1.w*d[7];
    als[i] = rs;
    ald[i] = rd;
}

// ---------------------------------------------------------------------------
// CSR build
// ---------------------------------------------------------------------------
__global__ void count_deg_kernel(const int* __restrict__ ei, int* __restrict__ deg,
                                 int E, int total)
{
    int e = blockIdx.x * 256 + threadIdx.x;
    if (e >= total) return;
    int dst = (e < E) ? ei[E + e] : (e - E);   // self-loop: dst = node
    atomicAdd(&deg[dst], 1);
}

__global__ void block_sums_kernel(const int* __restrict__ deg, int* __restrict__ partial, int n)
{
    int b = blockIdx.x, t = threadIdx.x;
    int base = b * 1024 + t * 4;
    int s = 0;
#pragma unroll
    for (int j = 0; j < 4; ++j) { int idx = base + j; s += (idx < n) ? deg[idx] : 0; }
    for (int off = 32; off > 0; off >>= 1) s += __shfl_down(s, off, 64);
    __shared__ int ws[4];
    if ((t & 63) == 0) ws[t >> 6] = s;
    __syncthreads();
    if (t == 0) partial[b] = ws[0] + ws[1] + ws[2] + ws[3];
}

__global__ void scan_partials_kernel(const int* __restrict__ partial,
                                     int* __restrict__ blockoff, int nb)
{
    if (threadIdx.x == 0 && blockIdx.x == 0) {
        int s = 0;
        for (int i = 0; i < nb; ++i) { blockoff[i] = s; s += partial[i]; }
    }
}

__global__ void scan_block_kernel(const int* __restrict__ deg,
                                  const int* __restrict__ blockoff,
                                  int* __restrict__ offsets, int* __restrict__ cursor,
                                  int n, int total)
{
    __shared__ int sdata[256];
    int b = blockIdx.x, t = threadIdx.x;
    int base = b * 1024 + t * 4;
    int v[4];
    int s = 0;
#pragma unroll
    for (int j = 0; j < 4; ++j) { int idx = base + j; v[j] = (idx < n) ? deg[idx] : 0; s += v[j]; }
    sdata[t] = s;
    __syncthreads();
    for (int off = 1; off < 256; off <<= 1) {
        int x = (t >= off) ? sdata[t - off] : 0;
        __syncthreads();
        sdata[t] += x;
        __syncthreads();
    }
    int run = ((t == 0) ? 0 : sdata[t - 1]) + blockoff[b];
#pragma unroll
    for (int j = 0; j < 4; ++j) {
        int idx = base + j;
        if (idx < n) { offsets[idx] = run; cursor[idx] = run; }
        run += v[j];
    }
    if (b == 0 && t == 0) offsets[n] = total;
}

__global__ void scatter_kernel(const int* __restrict__ ei, int* __restrict__ cursor,
                               int* __restrict__ csr, int E, int total)
{
    int e = blockIdx.x * 256 + threadIdx.x;
    if (e >= total) return;
    int src, dst;
    if (e < E) { src = ei[e]; dst = ei[E + e]; }
    else       { src = dst = e - E; }
    int p = atomicAdd(&cursor[dst], 1);
    csr[p] = src;
}

// ---------------------------------------------------------------------------
// agg1: one wave per dst node.  lane = h*8+c.  Edge loop unrolled x4 for MLP.
// out = elu( (sum_e ee*hp1[src]) / (sum_e ee) + b1 )
// ---------------------------------------------------------------------------
__global__ __launch_bounds__(256) void agg1_kernel(
    const float* __restrict__ hp1,
    const float* __restrict__ als, const float* __restrict__ ald,
    const int* __restrict__ offsets, const int* __restrict__ csr,
    const float* __restrict__ b1,
    float* __restrict__ h1, int n)
{
    int node = blockIdx.x * 4 + (threadIdx.x >> 6);
    if (node >= n) return;
    int lane = threadIdx.x & 63;
    int h = lane >> 3;

    int beg = offsets[node], end = offsets[node + 1];
    float ad = ald[node * 8 + h];
    float den = 0.f, acc = 0.f;

    int i = beg;
    for (; i + 4 <= end; i += 4) {
        // batch the index loads, then 8 independent gathers in flight
        int s0 = csr[i + 0], s1 = csr[i + 1], s2 = csr[i + 2], s3 = csr[i + 3];
        float a0 = als[s0 * 8 + h];
        float a1 = als[s1 * 8 + h];
        float a2 = als[s2 * 8 + h];
        float a3 = als[s3 * 8 + h];
        float v0 = hp1[(size_t)s0 * D1 + lane];
        float v1 = hp1[(size_t)s1 * D1 + lane];
        float v2 = hp1[(size_t)s2 * D1 + lane];
        float v3 = hp1[(size_t)s3 * D1 + lane];
        float e0 = a0 + ad; e0 = (e0 > 0.f) ? e0 : SLOPE * e0;
        float e1 = a1 + ad; e1 = (e1 > 0.f) ? e1 : SLOPE * e1;
        float e2 = a2 + ad; e2 = (e2 > 0.f) ? e2 : SLOPE * e2;
        float e3 = a3 + ad; e3 = (e3 > 0.f) ? e3 : SLOPE * e3;
        float w0 = __expf(e0), w1 = __expf(e1), w2 = __expf(e2), w3 = __expf(e3);
        den += (w0 + w1) + (w2 + w3);
        acc = fmaf(w0, v0, acc);
        acc = fmaf(w1, v1, acc);
        acc = fmaf(w2, v2, acc);
        acc = fmaf(w3, v3, acc);
    }
    for (; i < end; ++i) {
        int s = csr[i];
        float e = als[s * 8 + h] + ad;
        e = (e > 0.f) ? e : SLOPE * e;
        float ee = __expf(e);
        den += ee;
        acc = fmaf(ee, hp1[(size_t)s * D1 + lane], acc);
    }
    float v = acc / den + b1[lane];
    v = (v > 0.f) ? v : (__expf(v) - 1.f);    // ELU
    h1[(size_t)node * D1 + lane] = v;
}

// ---------------------------------------------------------------------------
// GEMM2 + fused al2: hp2[N,16] = h1[N,64] @ W2[64,16]; als2/ald2 via shuffles
// ---------------------------------------------------------------------------
__global__ __launch_bounds__(256) void gemm2_kernel(
    const float* __restrict__ H, const float* __restrict__ W2,
    const float* __restrict__ a2s, const float* __restrict__ a2d,
    float* __restrict__ HP2, float* __restrict__ als2, float* __restrict__ ald2,
    int n)
{
    __shared__ float Ws[64 * 16];
    int t = threadIdx.x;
    for (int i = t; i < 1024; i += 256) Ws[i] = W2[i];
    __syncthreads();
    int idx = blockIdx.x * 256 + t;        // node*16 + c
    int node = idx >> 4, c = idx & 15;
    if (node >= n) return;
    const float* hr = H + (size_t)node * D1;
    float acc = 0.f;
#pragma unroll 8
    for (int k = 0; k < 64; ++k) acc = fmaf(hr[k], Ws[k * 16 + c], acc);
    HP2[idx] = acc;

    // fused al2: width-16 reduction of acc*a2s / acc*a2d
    float rs = acc * a2s[c];
    float rd = acc * a2d[c];
    rs += __shfl_xor(rs, 8, 16);  rd += __shfl_xor(rd, 8, 16);
    rs += __shfl_xor(rs, 4, 16);  rd += __shfl_xor(rd, 4, 16);
    rs += __shfl_xor(rs, 2, 16);  rd += __shfl_xor(rd, 2, 16);
    rs += __shfl_xor(rs, 1, 16);  rd += __shfl_xor(rd, 1, 16);
    if (c == 0) { als2[node] = rs; ald2[node] = rd; }
}

// ---------------------------------------------------------------------------
// agg2 + log_softmax: 16 lanes per dst node (4 nodes per wave), unrolled x4
// ---------------------------------------------------------------------------
__global__ __launch_bounds__(256) void agg2_kernel(
    const float* __restrict__ hp2,
    const float* __restrict__ als, const float* __restrict__ ald,
    const int* __restrict__ offsets, const int* __restrict__ csr,
    const float* __restrict__ b2,
    float* __restrict__ out, int n)
{
    int node = blockIdx.x * 16 + (threadIdx.x >> 4);
    if (node >= n) return;
    int c = threadIdx.x & 15;

    int beg = offsets[node], end = offsets[node + 1];
    float ad = ald[node];
    float den = 0.f, acc = 0.f;

    int i = beg;
    for (; i + 4 <= end; i += 4) {
        int s0 = csr[i + 0], s1 = csr[i + 1], s2 = csr[i + 2], s3 = csr[i + 3];
        float a0 = als[s0], a1 = als[s1], a2 = als[s2], a3 = als[s3];
        float v0 = hp2[(size_t)s0 * 16 + c];
        float v1 = hp2[(size_t)s1 * 16 + c];
        float v2 = hp2[(size_t)s2 * 16 + c];
        float v3 = hp2[(size_t)s3 * 16 + c];
        float e0 = a0 + ad; e0 = (e0 > 0.f) ? e0 : SLOPE * e0;
        float e1 = a1 + ad; e1 = (e1 > 0.f) ? e1 : SLOPE * e1;
        float e2 = a2 + ad; e2 = (e2 > 0.f) ? e2 : SLOPE * e2;
        float e3 = a3 + ad; e3 = (e3 > 0.f) ? e3 : SLOPE * e3;
        float w0 = __expf(e0), w1 = __expf(e1), w2 = __expf(e2), w3 = __expf(e3);
        den += (w0 + w1) + (w2 + w3);
        acc = fmaf(w0, v0, acc);
        acc = fmaf(w1, v1, acc);
        acc = fmaf(w2, v2, acc);
        acc = fmaf(w3, v3, acc);
    }
    for (; i < end; ++i) {
        int s = csr[i];
        float e = als[s] + ad;
        e = (e > 0.f) ? e : SLOPE * e;
        float ee = __expf(e);
        den += ee;
        acc = fmaf(ee, hp2[(size_t)s * 16 + c], acc);
    }
    float v = acc / den + b2[c];

    // log_softmax over the 16 lanes of this node
    float m = v;
    m = fmaxf(m, __shfl_xor(m, 8, 16));
    m = fmaxf(m, __shfl_xor(m, 4, 16));
    m = fmaxf(m, __shfl_xor(m, 2, 16));
    m = fmaxf(m, __shfl_xor(m, 1, 16));
    float ex = __expf(v - m);
    float sum = ex;
    sum += __shfl_xor(sum, 8, 16);
    sum += __shfl_xor(sum, 4, 16);
    sum += __shfl_xor(sum, 2, 16);
    sum += __shfl_xor(sum, 1, 16);
    out[(size_t)node * 16 + c] = v - m - __logf(sum);
}

// ---------------------------------------------------------------------------
extern "C" void kernel_launch(void* const* d_in, const int* in_sizes, int n_in,
                              void* d_out, int out_size, void* d_ws, size_t ws_size,
                              hipStream_t stream)
{
    const float* x      = (const float*)d_in[0];
    const int*   ei     = (const int*)  d_in[1];
    const float* W1     = (const float*)d_in[2];
    const float* a1_src = (const float*)d_in[3];
    const float* a1_dst = (const float*)d_in[4];
    const float* b1     = (const float*)d_in[5];
    const float* W2     = (const float*)d_in[6];
    const float* a2_src = (const float*)d_in[7];
    const float* a2_dst = (const float*)d_in[8];
    const float* b2     = (const float*)d_in[9];
    float* out = (float*)d_out;

    const int N = in_sizes[0] / F_IN;       // 100000
    const int E = in_sizes[1] / 2;          // 1600000
    const int TOT = E + N;                  // edges incl self-loops

    // workspace carve-up (256B aligned)
    char* base = (char*)d_ws;
    size_t off = 0;
    auto carve = [&](size_t bytes) -> char* {
        char* p = base + off;
        off += (bytes + 255) & ~(size_t)255;
        return p;
    };
    float* hp1     = (float*)carve((size_t)N * D1 * 4);
    float* h1      = (float*)carve((size_t)N * D1 * 4);
    float* hp2     = (float*)carve((size_t)N * 16 * 4);
    float* als1    = (float*)carve((size_t)N * 8 * 4);
    float* ald1    = (float*)carve((size_t)N * 8 * 4);
    float* als2    = (float*)carve((size_t)N * 4);
    float* ald2    = (float*)carve((size_t)N * 4);
    int*   deg     = (int*)  carve((size_t)N * 4);
    int*   offsets = (int*)  carve((size_t)(N + 1) * 4);
    int*   cursor  = (int*)  carve((size_t)N * 4);
    int*   partial = (int*)  carve(4096);
    int*   blockoff= (int*)  carve(4096);
    int*   csr     = (int*)  carve((size_t)TOT * 4);

    const int nScanBlocks = (N + 1023) / 1024;       // 98
    const int nEdgeBlocks = (TOT + 255) / 256;

    hipMemsetAsync(deg, 0, (size_t)N * 4, stream);

    gemm1_kernel<<<(N + 63) / 64, 256, 0, stream>>>(x, W1, hp1, N);
    al1_kernel<<<(N * 8 + 255) / 256, 256, 0, stream>>>(hp1, a1_src, a1_dst, als1, ald1, N * 8);

    count_deg_kernel<<<nEdgeBlocks, 256, 0, stream>>>(ei, deg, E, TOT);
    block_sums_kernel<<<nScanBlocks, 256, 0, stream>>>(deg, partial, N);
    scan_partials_kernel<<<1, 64, 0, stream>>>(partial, blockoff, nScanBlocks);
    scan_block_kernel<<<nScanBlocks, 256, 0, stream>>>(deg, blockoff, offsets, cursor, N, TOT);
    scatter_kernel<<<nEdgeBlocks, 256, 0, stream>>>(ei, cursor, csr, E, TOT);

    agg1_kernel<<<(N + 3) / 4, 256, 0, stream>>>(hp1, als1, ald1, offsets, csr, b1, h1, N);

    gemm2_kernel<<<(N * 16 + 255) / 256, 256, 0, stream>>>(h1, W2, a2_src, a2_dst, hp2, als2, ald2, N);

    agg2_kernel<<<(N + 15) / 16, 256, 0, stream>>>(hp2, als2, ald2, offsets, csr, b2, out, N);
}